// Round 13
// baseline (101.063 us; speedup 1.0000x reference)
//
#include <hip/hip_runtime.h>

typedef float f32x4 __attribute__((ext_vector_type(4)));
typedef __bf16 bf16x8 __attribute__((ext_vector_type(8)));
typedef unsigned short u16x4 __attribute__((ext_vector_type(4)));
typedef unsigned int u32x2 __attribute__((ext_vector_type(2)));

constexpr int V  = 4096;
constexpr int KS = 10;              // K-split: 6 slabs x 384 + 4 slabs x 448
constexpr int NSLAB = 3 * KS;       // 30 partial slabs

__device__ __forceinline__ unsigned short f2bf(float f) {
    unsigned int u = __float_as_uint(f);
    u += 0x7FFFu + ((u >> 16) & 1u);           // round-to-nearest-even
    return (unsigned short)(u >> 16);
}
__device__ __forceinline__ float bf2f(unsigned short h) {
    return __uint_as_float(((unsigned int)h) << 16);
}

// ---- kernel 1: z = W @ xv + b  -> bf16 row-major (384 x 4096) ----------
__global__ __launch_bounds__(256) void k_z(const float* __restrict__ x,
                                           const float* __restrict__ W,
                                           const float* __restrict__ b,
                                           unsigned short* __restrict__ zb) {
    __shared__ float Ws[8 * 128];
    __shared__ float bs[8];
    const int rg = blockIdx.x;
    const int vb = blockIdx.y;
    const int t  = threadIdx.x;
    reinterpret_cast<f32x4*>(Ws)[t] = reinterpret_cast<const f32x4*>(W + rg * 1024)[t];
    if (t < 8) bs[t] = b[rg * 8 + t];
    __syncthreads();
    const int v = vb * 1024 + t * 4;
    f32x4 acc[8] = {};
    #pragma unroll 8
    for (int j = 0; j < 128; ++j) {
        f32x4 xv = *reinterpret_cast<const f32x4*>(x + (size_t)j * V + v);
        #pragma unroll
        for (int q = 0; q < 8; ++q) acc[q] += Ws[q * 128 + j] * xv;
    }
    #pragma unroll
    for (int q = 0; q < 8; ++q) {
        u16x4 u;
        #pragma unroll
        for (int j = 0; j < 4; ++j) u[j] = f2bf(acc[q][j] + bs[q]);
        *reinterpret_cast<u16x4*>(zb + (size_t)(rg * 8 + q) * V + v) = u;
    }
}

// ---- kernel 2: partial[p,kh] = bf16( z[p] @ A[p][k-slab] ) -------------
// grid (8 nt, 3 p, 10 kh) = 240 blocks, 512 thr = 8 waves (2M x 4N).
// Tile 128M x 512N, BK=32. Each wave reads its A-rows as 2 back-to-back
// 1 KB instructions = 2 KB CONTIGUOUS per row (r7's contiguity lever, 2x),
// 8 waves/CU double outstanding bytes and halve barrier frequency.
__global__ __launch_bounds__(512, 1) void k_gemm(const unsigned short* __restrict__ zb,
                                                 const float* __restrict__ A,
                                                 unsigned short* __restrict__ partial) {
    // [buf][n(512)][kpair(16) @ pitch 20 u32] = 80 KB.
    // kpair-SLOT swizzle (slot = kpair pair, b64 granule): stored slot =
    // logical slot ^ ((n>>3)&6) — even XOR keeps b128 reads aligned and
    // preserves k-order within fragments.
    __shared__ unsigned int Bt[2][512][20];

    const int nt = blockIdx.x;     // 0..7
    const int p  = blockIdx.y;     // 0..2
    const int kh = blockIdx.z;     // 0..9
    const int n0    = nt * 512;
    const int kbase = (kh < 6) ? kh * 384 : 2304 + (kh - 6) * 448;
    const int kend  = kbase + ((kh < 6) ? 384 : 448);   // 12 or 14 phases (even)

    const int t  = threadIdx.x;
    const int w  = t >> 6;         // 0..7
    const int l  = t & 63;
    const int wm = w >> 2;         // 0..1 (M half)
    const int wn = w & 3;          // 0..3 (N quarter)
    const int lrow = l & 15, g = l >> 4;

    // A staging: wave w owns rows K+w*4+j (j=0..3); row read as 2x1KB contiguous
    const float* Ab = A + (size_t)p * V * V + (size_t)(w * 4) * V + n0 + l * 4;
    // z fragments: rows p*128 + wm*64 + mt*16 + lrow, cols K + g*8
    const unsigned short* Zb = zb + ((size_t)p * 128 + wm * 64 + lrow) * V + g * 8;
    const int wsl = (l >> 1) & 6;  // write-side slot XOR (= (n>>3)&6 for n=4l+q)

    f32x4 acc[4][8] = {};
    f32x4 arA[4][2], arB[4][2];
    bf16x8 zr[4];

#define LOADA(AR, K) { _Pragma("unroll") for (int j = 0; j < 4; ++j) { \
        AR[j][0] = *reinterpret_cast<const f32x4*>(Ab + (size_t)((K) + j) * V); \
        AR[j][1] = *reinterpret_cast<const f32x4*>(Ab + (size_t)((K) + j) * V + 256); } }

#define LOADZ(K) { _Pragma("unroll") for (int mt = 0; mt < 4; ++mt) \
        zr[mt] = *reinterpret_cast<const bf16x8*>(Zb + (size_t)mt * 16 * V + (K)); }

    // rows w*4+{0,1} -> kpair 2w (slot w word 0); rows w*4+{2,3} -> kpair 2w+1
#define WRITEB(B, AR) { const int s_ = 2 * (w ^ wsl); \
        _Pragma("unroll") for (int h = 0; h < 2; ++h) \
        _Pragma("unroll") for (int q = 0; q < 4; ++q) { \
            u32x2 pk; \
            asm("v_cvt_pk_bf16_f32 %0, %1, %2" : "=v"(pk[0]) : "v"(AR[0][h][q]), "v"(AR[1][h][q])); \
            asm("v_cvt_pk_bf16_f32 %0, %1, %2" : "=v"(pk[1]) : "v"(AR[2][h][q]), "v"(AR[3][h][q])); \
            *reinterpret_cast<u32x2*>(&Bt[B][h * 256 + l * 4 + q][s_]) = pk; } }

#define BAR asm volatile("s_waitcnt lgkmcnt(0)\n\ts_barrier" ::: "memory")

#define MFMAP(B) { _Pragma("unroll") for (int nn = 0; nn < 8; ++nn) { \
        const int n_ = wn * 128 + nn * 16 + lrow; \
        const int s0_ = (2 * g) ^ ((n_ >> 3) & 6); \
        bf16x8 bf = *reinterpret_cast<const bf16x8*>(&Bt[B][n_][2 * s0_]); \
        _Pragma("unroll") for (int mt = 0; mt < 4; ++mt) \
            acc[mt][nn] = __builtin_amdgcn_mfma_f32_16x16x32_bf16(zr[mt], bf, acc[mt][nn], 0, 0, 0); } }

    // prologue
    LOADA(arA, kbase);
    LOADZ(kbase);

    for (int k0 = kbase; k0 < kend; k0 += 64) {
        const bool pf = (k0 + 64) < kend;
        // phase 0: consume arA,zr(k0); prefetch arB(k0+32); reload zr after use
        WRITEB(0, arA);              // waits only arA's vmcnt
        LOADA(arB, k0 + 32);
        BAR;
        MFMAP(0);
        LOADZ(k0 + 32);
        // phase 1: consume arB,zr(k0+32); prefetch arA(k0+64)
        WRITEB(1, arB);
        if (pf) LOADA(arA, k0 + 64);
        BAR;
        MFMAP(1);
        if (pf) LOADZ(k0 + 64);
    }

    // C/D layout: col = lane&15 (n), row = g*4 + reg (m)  [verified r1..r12]
    unsigned short* Pp = partial + (size_t)(p * KS + kh) * 128 * V;
    #pragma unroll
    for (int mt = 0; mt < 4; ++mt)
        #pragma unroll
        for (int nn = 0; nn < 8; ++nn) {
            const size_t base = (size_t)(wm * 64 + mt * 16 + g * 4) * V
                              + n0 + wn * 128 + nn * 16 + lrow;
            #pragma unroll
            for (int r = 0; r < 4; ++r)
                Pp[base + (size_t)r * V] = f2bf(acc[mt][nn][r]);
        }
#undef LOADA
#undef LOADZ
#undef WRITEB
#undef BAR
#undef MFMAP
}

// ---- kernel 3: out = relu(x + sum(fifo[:48 slabs]) + sum(30 bf16 partials))
__global__ __launch_bounds__(256) void k_epi(const float* __restrict__ x,
                                             const float* __restrict__ fifo,
                                             const unsigned short* __restrict__ partial,
                                             float* __restrict__ out) {
    const size_t off  = ((size_t)blockIdx.x * 256 + threadIdx.x) * 4;
    const size_t slab = (size_t)128 * V;
    f32x4 s0 = *reinterpret_cast<const f32x4*>(x + off);
    f32x4 s1 = {}, s2 = {}, s3 = {};
    #pragma unroll
    for (int s = 0; s < 48; ++s) {   // fifo[:16] x 3p = first 48 slabs
        f32x4 fv = *reinterpret_cast<const f32x4*>(fifo + (size_t)s * slab + off);
        switch (s & 3) {
            case 0: s0 += fv; break;
            case 1: s1 += fv; break;
            case 2: s2 += fv; break;
            default: s3 += fv; break;
        }
    }
    #pragma unroll
    for (int q = 0; q < NSLAB; ++q) {
        u16x4 pv = *reinterpret_cast<const u16x4*>(partial + (size_t)q * slab + off);
        f32x4 d;
        #pragma unroll
        for (int j = 0; j < 4; ++j) d[j] = bf2f(pv[j]);
        if (q & 1) s1 += d; else s2 += d;
    }
    f32x4 sum = (s0 + s1) + (s2 + s3);
    f32x4 o;
    #pragma unroll
    for (int j = 0; j < 4; ++j) o[j] = fmaxf(sum[j], 0.0f);
    *reinterpret_cast<f32x4*>(out + off) = o;
}

extern "C" void kernel_launch(void* const* d_in, const int* in_sizes, int n_in,
                              void* d_out, int out_size, void* d_ws, size_t ws_size,
                              hipStream_t stream) {
    const float* x    = (const float*)d_in[0];   // (1,128,4096,1)
    const float* A    = (const float*)d_in[1];   // (3,4096,4096)
    const float* fifo = (const float*)d_in[2];   // (17,3,128,4096)
    const float* W    = (const float*)d_in[3];   // (384,128)
    const float* b    = (const float*)d_in[4];   // (384,)
    float* out = (float*)d_out;                  // (1,128,4096) f32

    unsigned short* zb      = (unsigned short*)d_ws;                                    // 3 MB bf16
    unsigned short* partial = (unsigned short*)((char*)d_ws + (size_t)3 * 1024 * 1024); // 30 MB bf16

    k_z   <<<dim3(48, 4),    256, 0, stream>>>(x, W, b, zb);
    k_gemm<<<dim3(8, 3, KS), 512, 0, stream>>>(zb, A, partial);
    k_epi <<<dim3(512),      256, 0, stream>>>(x, fifo, partial, out);
}

// Round 14
// 93.645 us; speedup vs baseline: 1.0792x; 1.0792x over previous
//
#include <hip/hip_runtime.h>

typedef float f32x4 __attribute__((ext_vector_type(4)));
typedef __bf16 bf16x8 __attribute__((ext_vector_type(8)));
typedef unsigned short u16x4 __attribute__((ext_vector_type(4)));
typedef unsigned int u32x4 __attribute__((ext_vector_type(4)));

constexpr int V  = 4096;
constexpr int KS = 5;               // K-split (slabs 832,832,832,832,768)
constexpr int NSLAB = 3 * KS;       // 15 partial slabs

__device__ __forceinline__ unsigned short f2bf(float f) {
    unsigned int u = __float_as_uint(f);
    u += 0x7FFFu + ((u >> 16) & 1u);           // round-to-nearest-even
    return (unsigned short)(u >> 16);
}
__device__ __forceinline__ float bf2f(unsigned short h) {
    return __uint_as_float(((unsigned int)h) << 16);
}

// ---- kernel 1: z = W @ xv + b  -> bf16 (384 x 4096) --------------------
__global__ __launch_bounds__(256) void k_z(const float* __restrict__ x,
                                           const float* __restrict__ W,
                                           const float* __restrict__ b,
                                           unsigned short* __restrict__ zb) {
    __shared__ float Ws[8 * 128];
    __shared__ float bs[8];
    const int rg = blockIdx.x;
    const int vb = blockIdx.y;
    const int t  = threadIdx.x;
    reinterpret_cast<f32x4*>(Ws)[t] = reinterpret_cast<const f32x4*>(W + rg * 1024)[t];
    if (t < 8) bs[t] = b[rg * 8 + t];
    __syncthreads();
    const int v = vb * 1024 + t * 4;
    f32x4 acc[8] = {};
    #pragma unroll 8
    for (int j = 0; j < 128; ++j) {
        f32x4 xv = *reinterpret_cast<const f32x4*>(x + (size_t)j * V + v);
        #pragma unroll
        for (int q = 0; q < 8; ++q) acc[q] += Ws[q * 128 + j] * xv;
    }
    #pragma unroll
    for (int q = 0; q < 8; ++q) {
        u16x4 u;
        #pragma unroll
        for (int j = 0; j < 4; ++j) u[j] = f2bf(acc[q][j] + bs[q]);
        *reinterpret_cast<u16x4*>(zb + (size_t)(rg * 8 + q) * V + v) = u;
    }
}

// ---- kernel 2: partial[p,kh] = bf16( z[p] @ A[p][k-slab] ) -------------
// r7 body (best known: 92.7 us) + per-block cyclic k-phase stagger:
// block starts its k-loop at a rotated offset so concurrent blocks read
// 16KB-strided rows at DECORRELATED phases (channel-aliasing probe).
__global__ __launch_bounds__(256, 2) void k_gemm(const unsigned short* __restrict__ zb,
                                                 const float* __restrict__ A,
                                                 unsigned short* __restrict__ partial) {
    // [buf][n(256)][kpair(16) @ pitch 20 u32]  = 40 KB total
    // kp-quad swizzle: stored kp = logical kp XOR (((n>>2)&3)<<2)
    __shared__ unsigned int Bt[2][256][20];

    const int nt = blockIdx.x;     // 0..15
    const int p  = blockIdx.y;     // 0..2
    const int kh = blockIdx.z;     // 0..4
    const int n0    = nt * 256;
    const int kbase = kh * 832;
    const int kend  = (kh == 4) ? 4096 : kbase + 832;
    const int niter = (kend - kbase) >> 6;          // 13 or 12 tile-iters

    const int t  = threadIdx.x;
    const int w  = t >> 6;
    const int l  = t & 63;
    const int wm = w >> 1, wn = w & 1;
    const int lrow = l & 15, g = l >> 4;

    // staging read base: rows k + w*8 + j, cols n0 + 4l (1 KB/wave-instr)
    const float* Ab = A + (size_t)p * V * V + (size_t)(w * 8) * V + n0 + l * 4;
    // staging write: n = 4l+q, kp-quad = 4*(w ^ (l&3)); one b128 per q
    const int wswz = (w ^ (l & 3)) << 2;
    // fragment read: n = wn*128 + nn*16 + lrow; swizzled kp-quad:
    const int gp = (g ^ ((lrow >> 2) & 3)) << 2;
    // z fragments: rows m = wm*64 + mt*16 + lrow, k-offset g*8
    const unsigned short* Zb = zb + ((size_t)p * 128 + wm * 64 + lrow) * V + g * 8;

    f32x4 acc[4][8] = {};
    f32x4 arA[8], arB[8];
    bf16x8 zr[4];

#define LOADA(AR, K) { _Pragma("unroll") for (int j = 0; j < 8; ++j) \
        AR[j] = *reinterpret_cast<const f32x4*>(Ab + (size_t)((K) + j) * V); }

#define LOADZ(K) { _Pragma("unroll") for (int mt = 0; mt < 4; ++mt) \
        zr[mt] = *reinterpret_cast<const bf16x8*>(Zb + (size_t)mt * 16 * V + (K)); }

#define WRITEB(B, AR) { _Pragma("unroll") for (int q = 0; q < 4; ++q) { \
        u32x4 pk; \
        asm("v_cvt_pk_bf16_f32 %0, %1, %2" : "=v"(pk[0]) : "v"(AR[0][q]), "v"(AR[1][q])); \
        asm("v_cvt_pk_bf16_f32 %0, %1, %2" : "=v"(pk[1]) : "v"(AR[2][q]), "v"(AR[3][q])); \
        asm("v_cvt_pk_bf16_f32 %0, %1, %2" : "=v"(pk[2]) : "v"(AR[4][q]), "v"(AR[5][q])); \
        asm("v_cvt_pk_bf16_f32 %0, %1, %2" : "=v"(pk[3]) : "v"(AR[6][q]), "v"(AR[7][q])); \
        *reinterpret_cast<u32x4*>(&Bt[B][l * 4 + q][wswz]) = pk; } }

#define BAR asm volatile("s_waitcnt lgkmcnt(0)\n\ts_barrier" ::: "memory")

#define MFMAP(B) { _Pragma("unroll") for (int nn = 0; nn < 8; ++nn) { \
        bf16x8 bf = *reinterpret_cast<const bf16x8*>(&Bt[B][wn * 128 + nn * 16 + lrow][gp]); \
        _Pragma("unroll") for (int mt = 0; mt < 4; ++mt) \
            acc[mt][nn] = __builtin_amdgcn_mfma_f32_16x16x32_bf16(zr[mt], bf, acc[mt][nn], 0, 0, 0); } }

    // cyclic k-phase stagger: start at rotated tile, wrap at kend -> kbase
    const int i0 = ((nt + 4 * p) * 5) % niter;
    int kk = kbase + i0 * 64;

    // prologue
    LOADA(arA, kk);
    LOADZ(kk);

    for (int i = 0; i < niter; ++i) {
        int kn = kk + 64; if (kn >= kend) kn = kbase;   // rotation wrap
        // phase 0: consume arA,zr(kk); prefetch arB(kk+32); reload zr after use
        WRITEB(0, arA);              // waits only arA's vmcnt
        LOADA(arB, kk + 32);
        BAR;
        MFMAP(0);
        LOADZ(kk + 32);
        // phase 1: consume arB,zr(kk+32); prefetch arA(kn)
        WRITEB(1, arB);
        LOADA(arA, kn);              // last iter: dead load of start tile (L2-hot)
        BAR;
        MFMAP(1);
        LOADZ(kn);
        kk = kn;
    }

    // C/D layout: col = lane&15 (n), row = g*4 + reg (m)  [verified r1..r13]
    unsigned short* Pp = partial + (size_t)(p * KS + kh) * 128 * V;
    #pragma unroll
    for (int mt = 0; mt < 4; ++mt)
        #pragma unroll
        for (int nn = 0; nn < 8; ++nn) {
            const size_t base = (size_t)(wm * 64 + mt * 16 + g * 4) * V
                              + n0 + wn * 128 + nn * 16 + lrow;
            #pragma unroll
            for (int r = 0; r < 4; ++r)
                Pp[base + (size_t)r * V] = f2bf(acc[mt][nn][r]);
        }
#undef LOADA
#undef LOADZ
#undef WRITEB
#undef BAR
#undef MFMAP
}

// ---- kernel 3: out = relu(x + sum(fifo[:48 slabs]) + sum(15 bf16 partials))
__global__ __launch_bounds__(256) void k_epi(const float* __restrict__ x,
                                             const float* __restrict__ fifo,
                                             const unsigned short* __restrict__ partial,
                                             float* __restrict__ out) {
    const size_t off  = ((size_t)blockIdx.x * 256 + threadIdx.x) * 4;
    const size_t slab = (size_t)128 * V;
    f32x4 s0 = *reinterpret_cast<const f32x4*>(x + off);
    f32x4 s1 = {}, s2 = {}, s3 = {};
    #pragma unroll
    for (int s = 0; s < 48; ++s) {   // fifo[:16] x 3p = first 48 slabs
        f32x4 fv = *reinterpret_cast<const f32x4*>(fifo + (size_t)s * slab + off);
        switch (s & 3) {
            case 0: s0 += fv; break;
            case 1: s1 += fv; break;
            case 2: s2 += fv; break;
            default: s3 += fv; break;
        }
    }
    #pragma unroll
    for (int q = 0; q < NSLAB; ++q) {
        u16x4 pv = *reinterpret_cast<const u16x4*>(partial + (size_t)q * slab + off);
        f32x4 d;
        #pragma unroll
        for (int j = 0; j < 4; ++j) d[j] = bf2f(pv[j]);
        if (q & 1) s1 += d; else s2 += d;
    }
    f32x4 sum = (s0 + s1) + (s2 + s3);
    f32x4 o;
    #pragma unroll
    for (int j = 0; j < 4; ++j) o[j] = fmaxf(sum[j], 0.0f);
    *reinterpret_cast<f32x4*>(out + off) = o;
}

extern "C" void kernel_launch(void* const* d_in, const int* in_sizes, int n_in,
                              void* d_out, int out_size, void* d_ws, size_t ws_size,
                              hipStream_t stream) {
    const float* x    = (const float*)d_in[0];   // (1,128,4096,1)
    const float* A    = (const float*)d_in[1];   // (3,4096,4096)
    const float* fifo = (const float*)d_in[2];   // (17,3,128,4096)
    const float* W    = (const float*)d_in[3];   // (384,128)
    const float* b    = (const float*)d_in[4];   // (384,)
    float* out = (float*)d_out;                  // (1,128,4096) f32

    unsigned short* zb      = (unsigned short*)d_ws;                                    // 3 MB bf16
    unsigned short* partial = (unsigned short*)((char*)d_ws + (size_t)3 * 1024 * 1024); // 15 MB bf16

    k_z   <<<dim3(48, 4),     256, 0, stream>>>(x, W, b, zb);
    k_gemm<<<dim3(16, 3, KS), 256, 0, stream>>>(zb, A, partial);
    k_epi <<<dim3(512),       256, 0, stream>>>(x, fifo, partial, out);
}